// Round 6
// baseline (303.389 us; speedup 1.0000x reference)
//
#include <hip/hip_runtime.h>

// BondWeight: out[b, src+1, dst+1] = w; out[b, dst+1, src+1] = w (two passes,
// last-write-wins within the 1024-write per-batch sequence, numpy semantics).
// B=1024, E=512, T=8, N=256. Output 268 MB f32. Write floor ~41 us @ 6.5 TB/s.
//
// R6: two kernels. R2-R5 (all ~neutral) emitted the 268 MB of stores only in
// the last phase of each block (after LDS zero + edge-load latency + CAS + 2-3
// barriers) -> store-pipe starvation suspect. Now:
//  A) pure grid-stride float4 zero-fill, structurally identical to the rocclr
//     fill that sustains 6.5 TB/s on this box: stores start at cycle ~0.
//  B) winner resolution per 64-row window (CAS-max on u16 seq table, 32 KB),
//     then the unique winning thread stores w straight to global (~1M
//     scattered dwords; RMW line fetches hit L3, which A just warmed).
// If this is ALSO neutral, the bench floor is harness-fixed (poison fill) and
// the kernel is at its roofline.

#define NB_E 512
#define NB_N 256
#define CH_ROWS 64
#define SEQ_WORDS (CH_ROWS * NB_N / 2)   // 8192 u32 = 32 KB LDS

__global__ __launch_bounds__(256) void bw_zero_fill(
    float4* __restrict__ o, int n4)
{
    const float4 z = make_float4(0.f, 0.f, 0.f, 0.f);
    for (int i = blockIdx.x * 256 + threadIdx.x; i < n4; i += gridDim.x * 256)
        o[i] = z;    // consecutive lanes -> consecutive 16B, full-line stores
}

__device__ __forceinline__ void lds_max_u16(unsigned int* tab, int cell, unsigned int v16)
{
    unsigned int* w = tab + (cell >> 1);
    const int sh = (cell & 1) * 16;
    unsigned int old = *w;
    while (true) {
        const unsigned int cur = (old >> sh) & 0xFFFFu;
        if (cur >= v16) break;                       // current winner is later
        const unsigned int nw = (old & ~(0xFFFFu << sh)) | (v16 << sh);
        const unsigned int seen = atomicCAS(w, old, nw);
        if (seen == old) break;
        old = seen;                                  // contended: retry
    }
}

__global__ __launch_bounds__(256) void bw_scatter(
    const float* __restrict__ weights,
    const int*   __restrict__ bsrc,
    const int*   __restrict__ bdst,
    const int*   __restrict__ btyp,
    float*       __restrict__ out)
{
    __shared__ unsigned int seqtab[SEQ_WORDS];

    const int bx = blockIdx.x;
    const int b  = bx >> 2;                 // batch
    const int r0 = (bx & 3) * CH_ROWS;      // my 64-row window
    const int t  = threadIdx.x;

    // --- zero seq table: 8192 u32, 8 x uint4 per thread ---
    {
        uint4* s4 = (uint4*)seqtab;
        #pragma unroll
        for (int k = 0; k < SEQ_WORDS / 4 / 256; ++k)
            s4[t + 256 * k] = make_uint4(0u, 0u, 0u, 0u);
    }

    // --- load my batch's edges: 2 per thread (int2, coalesced) ---
    // seq order: pass1 (src,dst) e=0..511 then pass2 (dst,src) e=0..511.
    // packed = (seq+1)<<3 | type (< 2^16); CAS-max == reference last-write-wins.
    const int2 s2 = ((const int2*)(bsrc + b * NB_E))[t];
    const int2 d2 = ((const int2*)(bdst + b * NB_E))[t];
    const int2 y2 = ((const int2*)(btyp + b * NB_E))[t];
    const float wA = weights[y2.x & 7];
    const float wB = weights[y2.y & 7];

    int cell[4]; unsigned int pk[4]; float wv[4]; bool inw[4];
    {
        const int e0 = 2 * t, e1 = 2 * t + 1;
        const int sa = s2.x + 1, da = d2.x + 1;      // [1,255]
        const int sb = s2.y + 1, db = d2.y + 1;
        const unsigned int ta = (unsigned int)y2.x & 7u;
        const unsigned int tb = (unsigned int)y2.y & 7u;
        const int rr[4] = { sa, sb, da, db };
        const int cc[4] = { da, db, sa, sb };
        const unsigned int qq[4] = {
            ((unsigned int)(e0 + 1) << 3) | ta,
            ((unsigned int)(e1 + 1) << 3) | tb,
            ((unsigned int)(NB_E + e0 + 1) << 3) | ta,
            ((unsigned int)(NB_E + e1 + 1) << 3) | tb };
        const float ww[4] = { wA, wB, wA, wB };
        #pragma unroll
        for (int i = 0; i < 4; ++i) {
            const int r = rr[i] - r0;
            inw[i]  = (0 <= r) && (r < CH_ROWS);
            cell[i] = r * NB_N + cc[i];
            pk[i]   = qq[i];
            wv[i]   = ww[i];
        }
    }

    __syncthreads();    // table zeroed

    #pragma unroll
    for (int i = 0; i < 4; ++i)
        if (inw[i]) lds_max_u16(seqtab, cell[i], pk[i]);

    __syncthreads();    // winners final

    // --- unique winner thread stores w straight to global (~256/block) ---
    float* __restrict__ tile = out + (size_t)b * (NB_N * NB_N) + r0 * NB_N;
    #pragma unroll
    for (int i = 0; i < 4; ++i) {
        if (inw[i]) {
            const unsigned int w32 = seqtab[cell[i] >> 1];
            const unsigned int cur = (w32 >> ((cell[i] & 1) * 16)) & 0xFFFFu;
            if (cur == pk[i]) tile[cell[i]] = wv[i];
        }
    }
}

extern "C" void kernel_launch(void* const* d_in, const int* in_sizes, int n_in,
                              void* d_out, int out_size, void* d_ws, size_t ws_size,
                              hipStream_t stream) {
    const float* weights = (const float*)d_in[0];   // [T=8]
    const int*   bsrc    = (const int*)d_in[1];     // [B, E]
    const int*   bdst    = (const int*)d_in[2];     // [B, E]
    const int*   btyp    = (const int*)d_in[3];     // [B, E]
    float*       out     = (float*)d_out;           // [B, N, N] f32

    const int nb = in_sizes[1] / NB_E;              // B = 1024
    const int n4 = (nb * NB_N * NB_N) / 4;          // 16.8M float4

    bw_zero_fill<<<4096, 256, 0, stream>>>((float4*)out, n4);
    bw_scatter<<<nb * 4, 256, 0, stream>>>(weights, bsrc, bdst, btyp, out);
}